// Round 8
// baseline (570.566 us; speedup 1.0000x reference)
//
#include <hip/hip_runtime.h>
#include <hip/hip_bf16.h>

// 2-layer GCN: norm (self-loops, sym D^-1/2), CSR build, GEMM, gather-aggregate.
// All f32. One wave per node for aggregation (no scatter atomics).
// R7 (resubmit — broker timeout): agg kernels use 1024-thread blocks (16
// waves/block, 6250 blocks) — R6 showed OccupancyPercent 55% with 4-wave
// blocks; 2 big blocks fill a CU's 32-wave cap and average degree imbalance.
// Agg structure otherwise identical to R6 (8x unroll, 8 accumulators, int2 csr).

static inline int cdiv(int a, int b) { return (a + b - 1) / b; }

// ---------------- CSR build ----------------

__global__ void k_init(int* __restrict__ cnt, int* __restrict__ cursor, int n) {
    int i = blockIdx.x * blockDim.x + threadIdx.x;
    if (i < n) { cnt[i] = 0; cursor[i] = 0; }
}

__global__ void k_deg(const int* __restrict__ col, int* __restrict__ cnt, int e) {
    int i = blockIdx.x * blockDim.x + threadIdx.x;
    if (i < e) atomicAdd(&cnt[col[i]], 1);
}

__global__ void k_dinv(const int* __restrict__ cnt, float* __restrict__ dinv, int n) {
    int i = blockIdx.x * blockDim.x + threadIdx.x;
    if (i < n) dinv[i] = rsqrtf((float)(cnt[i] + 1));  // +1 self-loop, always > 0
}

__global__ void k_scan1(const int* __restrict__ cnt, int* __restrict__ pref,
                        int* __restrict__ bsum, int n) {
    __shared__ int s[256];
    int t = threadIdx.x;
    int i = blockIdx.x * 256 + t;
    int v = (i < n) ? cnt[i] : 0;
    s[t] = v;
    __syncthreads();
    for (int off = 1; off < 256; off <<= 1) {
        int x = (t >= off) ? s[t - off] : 0;
        __syncthreads();
        s[t] += x;
        __syncthreads();
    }
    if (i < n) pref[i] = s[t] - v;  // exclusive within block
    if (t == 255) bsum[blockIdx.x] = s[255];
}

__global__ void k_scan2(const int* __restrict__ bsum, int* __restrict__ boff, int nb) {
    __shared__ int s[512];
    int t = threadIdx.x;
    int v = (t < nb) ? bsum[t] : 0;
    s[t] = v;
    __syncthreads();
    for (int off = 1; off < 512; off <<= 1) {
        int x = (t >= off) ? s[t - off] : 0;
        __syncthreads();
        s[t] += x;
        __syncthreads();
    }
    if (t < nb) boff[t] = s[t] - v;  // exclusive
}

__global__ void k_scan3(int* __restrict__ pref, const int* __restrict__ boff,
                        int n, int e_total) {
    int i = blockIdx.x * blockDim.x + threadIdx.x;
    if (i < n) pref[i] += boff[i >> 8];
    if (i == n) pref[n] = e_total;
}

__global__ void k_fill(const int* __restrict__ row, const int* __restrict__ col,
                       const int* __restrict__ indptr, int* __restrict__ cursor,
                       const float* __restrict__ dinv,
                       int2* __restrict__ csr, int e) {
    int i = blockIdx.x * blockDim.x + threadIdx.x;
    if (i >= e) return;
    int c = col[i], r = row[i];
    int pos = indptr[c] + atomicAdd(&cursor[c], 1);
    csr[pos] = make_int2(r, __float_as_int(dinv[r] * dinv[c]));
}

// ---------------- dense GEMM: H[n][COUT] = X[n][128] @ W[128][COUT] ----------------

template <int COUT>
__global__ __launch_bounds__(256) void gemm_k(const float* __restrict__ X,
                                              const float* __restrict__ W,
                                              float* __restrict__ H, int n) {
    constexpr int KT = 64;             // k-tile
    constexpr int CG = COUT / 4;       // thread groups along channels
    constexpr int MG = 256 / CG;       // thread groups along rows
    constexpr int TILE_M = MG * 4;
    __shared__ float xs[TILE_M][KT];
    __shared__ float ws[KT][COUT];
    const int t = threadIdx.x;
    const int m_base = blockIdx.x * TILE_M;
    const int tx = t % CG, ty = t / CG;
    const int c0 = tx * 4, m0 = ty * 4;
    float acc[4][4] = {};
    for (int kt = 0; kt < 128; kt += KT) {
        {   // stage W tile (KT x COUT), linear copy
            const float4* src = (const float4*)(W + (size_t)kt * COUT);
            float4* dst = (float4*)&ws[0][0];
            constexpr int NW = KT * COUT / 4 / 256;
#pragma unroll
            for (int i = 0; i < NW; i++) dst[t + i * 256] = src[t + i * 256];
        }
        {   // stage X tile (TILE_M x KT)
            float4* dst = (float4*)&xs[0][0];
            constexpr int NX = TILE_M * KT / 4 / 256;
#pragma unroll
            for (int i = 0; i < NX; i++) {
                int idx = t + i * 256;
                int m = idx >> 4, q = idx & 15;  // 16 float4 per row of KT
                int gm = m_base + m;
                float4 v = make_float4(0.f, 0.f, 0.f, 0.f);
                if (gm < n) v = ((const float4*)X)[(size_t)gm * 32 + (kt >> 2) + q];
                dst[idx] = v;
            }
        }
        __syncthreads();
#pragma unroll
        for (int k = 0; k < KT; k += 4) {
            float xr[4][4], wr[4][4];
#pragma unroll
            for (int mm = 0; mm < 4; mm++) {
                float4 v = *(const float4*)&xs[m0 + mm][k];
                xr[mm][0] = v.x; xr[mm][1] = v.y; xr[mm][2] = v.z; xr[mm][3] = v.w;
            }
#pragma unroll
            for (int kk = 0; kk < 4; kk++) {
                float4 v = *(const float4*)&ws[k + kk][c0];
                wr[kk][0] = v.x; wr[kk][1] = v.y; wr[kk][2] = v.z; wr[kk][3] = v.w;
            }
#pragma unroll
            for (int kk = 0; kk < 4; kk++)
#pragma unroll
                for (int mm = 0; mm < 4; mm++)
#pragma unroll
                    for (int cc = 0; cc < 4; cc++)
                        acc[mm][cc] = fmaf(xr[mm][kk], wr[kk][cc], acc[mm][cc]);
        }
        __syncthreads();
    }
#pragma unroll
    for (int mm = 0; mm < 4; mm++) {
        int gm = m_base + m0 + mm;
        if (gm < n) {
            float4 v = make_float4(acc[mm][0], acc[mm][1], acc[mm][2], acc[mm][3]);
            *(float4*)&H[(size_t)gm * COUT + c0] = v;
        }
    }
}

// ---------------- aggregation: one wave per node ----------------

// C=128: lane handles 2 channels via float2. relu(agg + b).
// Uniform control flow; 8x unroll, 8 independent accumulators. 16 waves/block.
__global__ __launch_bounds__(1024) void k_agg128(const float* __restrict__ h,
                                                 const int* __restrict__ indptr,
                                                 const int2* __restrict__ csr,
                                                 const float* __restrict__ dinv,
                                                 const float* __restrict__ bias,
                                                 float* __restrict__ out, int n) {
    int wid = (blockIdx.x * blockDim.x + threadIdx.x) >> 6;
    int lane = threadIdx.x & 63;
    if (wid >= n) return;
    const float2* hp = (const float2*)h;
    float di = dinv[wid];
    float wself = di * di;
    float2 hv = hp[(size_t)wid * 64 + lane];
    float2 a[8];
#pragma unroll
    for (int k = 0; k < 8; k++) a[k] = make_float2(0.f, 0.f);
    a[0].x = wself * hv.x;
    a[0].y = wself * hv.y;
    int e = indptr[wid], e1 = indptr[wid + 1];
    for (; e + 8 <= e1; e += 8) {
        int2 c[8];
#pragma unroll
        for (int k = 0; k < 8; k++) c[k] = csr[e + k];
#pragma unroll
        for (int k = 0; k < 8; k++) {
            float nr = __int_as_float(c[k].y);
            float2 v = hp[(size_t)c[k].x * 64 + lane];
            a[k].x = fmaf(nr, v.x, a[k].x);
            a[k].y = fmaf(nr, v.y, a[k].y);
        }
    }
    for (; e < e1; e++) {
        int2 ck = csr[e];
        float nr = __int_as_float(ck.y);
        float2 v = hp[(size_t)ck.x * 64 + lane];
        a[0].x = fmaf(nr, v.x, a[0].x);
        a[0].y = fmaf(nr, v.y, a[0].y);
    }
    float sx = ((a[0].x + a[1].x) + (a[2].x + a[3].x)) +
               ((a[4].x + a[5].x) + (a[6].x + a[7].x));
    float sy = ((a[0].y + a[1].y) + (a[2].y + a[3].y)) +
               ((a[4].y + a[5].y) + (a[6].y + a[7].y));
    float2 b = ((const float2*)bias)[lane];
    ((float2*)(out + (size_t)wid * 128))[lane] =
        make_float2(fmaxf(sx + b.x, 0.f), fmaxf(sy + b.y, 0.f));
}

// C=64: lane handles 1 channel. out = agg + b (no relu). Same 8x unroll.
__global__ __launch_bounds__(1024) void k_agg64(const float* __restrict__ h,
                                                const int* __restrict__ indptr,
                                                const int2* __restrict__ csr,
                                                const float* __restrict__ dinv,
                                                const float* __restrict__ bias,
                                                float* __restrict__ out, int n) {
    int wid = (blockIdx.x * blockDim.x + threadIdx.x) >> 6;
    int lane = threadIdx.x & 63;
    if (wid >= n) return;
    float di = dinv[wid];
    float a[8];
#pragma unroll
    for (int k = 0; k < 8; k++) a[k] = 0.f;
    a[0] = di * di * h[(size_t)wid * 64 + lane];
    int e = indptr[wid], e1 = indptr[wid + 1];
    for (; e + 8 <= e1; e += 8) {
        int2 c[8];
#pragma unroll
        for (int k = 0; k < 8; k++) c[k] = csr[e + k];
#pragma unroll
        for (int k = 0; k < 8; k++) {
            float nr = __int_as_float(c[k].y);
            a[k] = fmaf(nr, h[(size_t)c[k].x * 64 + lane], a[k]);
        }
    }
    for (; e < e1; e++) {
        int2 ck = csr[e];
        float nr = __int_as_float(ck.y);
        a[0] = fmaf(nr, h[(size_t)ck.x * 64 + lane], a[0]);
    }
    float s = ((a[0] + a[1]) + (a[2] + a[3])) + ((a[4] + a[5]) + (a[6] + a[7]));
    out[(size_t)wid * 64 + lane] = s + bias[lane];
}

// ---------------- launch ----------------

extern "C" void kernel_launch(void* const* d_in, const int* in_sizes, int n_in,
                              void* d_out, int out_size, void* d_ws, size_t ws_size,
                              hipStream_t stream) {
    const float* x  = (const float*)d_in[0];
    const int* ei   = (const int*)d_in[1];
    const float* W1 = (const float*)d_in[2];
    const float* b1 = (const float*)d_in[3];
    const float* W2 = (const float*)d_in[4];
    const float* b2 = (const float*)d_in[5];
    float* out = (float*)d_out;

    const int N = in_sizes[0] / 128;
    const int E = in_sizes[1] / 2;
    const int* row = ei;       // edge_index[0] = source
    const int* col = ei + E;   // edge_index[1] = target

    char* p = (char*)d_ws;
    auto carve = [&](size_t bytes) -> void* {
        void* r = (void*)p;
        p += (bytes + 255) & ~(size_t)255;
        return r;
    };
    int*   cnt      = (int*)carve((size_t)N * 4);
    float* dinv     = (float*)carve((size_t)N * 4);
    int*   indptr   = (int*)carve((size_t)(N + 1) * 4);
    int*   bsum     = (int*)carve(512 * 4);
    int*   boff     = (int*)carve(512 * 4);
    int*   cursor   = (int*)carve((size_t)N * 4);
    int2*  csr      = (int2*)carve((size_t)E * 8);
    float* h        = (float*)carve((size_t)N * 128 * 4);
    float* h1       = (float*)carve((size_t)N * 128 * 4);
    float* h2       = h;  // reuse: h dead after agg1

    const int NB = cdiv(N, 256);  // scan blocks (391 <= 512)

    k_init<<<cdiv(N, 256), 256, 0, stream>>>(cnt, cursor, N);
    k_deg<<<cdiv(E, 256), 256, 0, stream>>>(col, cnt, E);
    k_dinv<<<cdiv(N, 256), 256, 0, stream>>>(cnt, dinv, N);
    k_scan1<<<NB, 256, 0, stream>>>(cnt, indptr, bsum, N);
    k_scan2<<<1, 512, 0, stream>>>(bsum, boff, NB);
    k_scan3<<<cdiv(N + 1, 256), 256, 0, stream>>>(indptr, boff, N, E);
    k_fill<<<cdiv(E, 256), 256, 0, stream>>>(row, col, indptr, cursor, dinv,
                                             csr, E);

    // layer 1: h = x@W1 ; h1 = relu(agg(h) + b1)
    gemm_k<128><<<cdiv(N, 32), 256, 0, stream>>>(x, W1, h, N);
    k_agg128<<<cdiv(N, 16), 1024, 0, stream>>>(h, indptr, csr, dinv, b1, h1, N);
    // layer 2: h2 = h1@W2 ; out = agg(h2) + b2
    gemm_k<64><<<cdiv(N, 64), 256, 0, stream>>>(h1, W2, h2, N);
    k_agg64<<<cdiv(N, 16), 1024, 0, stream>>>(h2, indptr, csr, dinv, b2, out, N);
}

// Round 9
// 470.141 us; speedup vs baseline: 1.2136x; 1.2136x over previous
//
#include <hip/hip_runtime.h>
#include <hip/hip_bf16.h>

// 2-layer GCN: norm (self-loops, sym D^-1/2), CSR build, GEMM, gather-aggregate.
// R9: agg blocks back to 256 threads (R8 proved 1024 regresses: 153 vs 129us).
// GEMM outputs h/h2 stored as bf16 -> gather bytes halved (819->410MB layer1,
// 410->205MB layer2); f32 accumulate. 8x unroll, 8 accumulators, int2 csr.

static inline int cdiv(int a, int b) { return (a + b - 1) / b; }

__device__ inline unsigned short f2bf(float f) {
    __hip_bfloat16 b = __float2bfloat16(f);
    return *(unsigned short*)&b;
}
__device__ inline float2 bf2_to_f2(unsigned int u) {
    return make_float2(__uint_as_float(u << 16),
                       __uint_as_float(u & 0xffff0000u));
}
__device__ inline float bf_to_f(unsigned short u) {
    return __uint_as_float(((unsigned int)u) << 16);
}

// ---------------- CSR build ----------------

__global__ void k_init(int* __restrict__ cnt, int* __restrict__ cursor, int n) {
    int i = blockIdx.x * blockDim.x + threadIdx.x;
    if (i < n) { cnt[i] = 0; cursor[i] = 0; }
}

__global__ void k_deg(const int* __restrict__ col, int* __restrict__ cnt, int e) {
    int i = blockIdx.x * blockDim.x + threadIdx.x;
    if (i < e) atomicAdd(&cnt[col[i]], 1);
}

__global__ void k_dinv(const int* __restrict__ cnt, float* __restrict__ dinv, int n) {
    int i = blockIdx.x * blockDim.x + threadIdx.x;
    if (i < n) dinv[i] = rsqrtf((float)(cnt[i] + 1));  // +1 self-loop, always > 0
}

__global__ void k_scan1(const int* __restrict__ cnt, int* __restrict__ pref,
                        int* __restrict__ bsum, int n) {
    __shared__ int s[256];
    int t = threadIdx.x;
    int i = blockIdx.x * 256 + t;
    int v = (i < n) ? cnt[i] : 0;
    s[t] = v;
    __syncthreads();
    for (int off = 1; off < 256; off <<= 1) {
        int x = (t >= off) ? s[t - off] : 0;
        __syncthreads();
        s[t] += x;
        __syncthreads();
    }
    if (i < n) pref[i] = s[t] - v;  // exclusive within block
    if (t == 255) bsum[blockIdx.x] = s[255];
}

__global__ void k_scan2(const int* __restrict__ bsum, int* __restrict__ boff, int nb) {
    __shared__ int s[512];
    int t = threadIdx.x;
    int v = (t < nb) ? bsum[t] : 0;
    s[t] = v;
    __syncthreads();
    for (int off = 1; off < 512; off <<= 1) {
        int x = (t >= off) ? s[t - off] : 0;
        __syncthreads();
        s[t] += x;
        __syncthreads();
    }
    if (t < nb) boff[t] = s[t] - v;  // exclusive
}

__global__ void k_scan3(int* __restrict__ pref, const int* __restrict__ boff,
                        int n, int e_total) {
    int i = blockIdx.x * blockDim.x + threadIdx.x;
    if (i < n) pref[i] += boff[i >> 8];
    if (i == n) pref[n] = e_total;
}

__global__ void k_fill(const int* __restrict__ row, const int* __restrict__ col,
                       const int* __restrict__ indptr, int* __restrict__ cursor,
                       const float* __restrict__ dinv,
                       int2* __restrict__ csr, int e) {
    int i = blockIdx.x * blockDim.x + threadIdx.x;
    if (i >= e) return;
    int c = col[i], r = row[i];
    int pos = indptr[c] + atomicAdd(&cursor[c], 1);
    csr[pos] = make_int2(r, __float_as_int(dinv[r] * dinv[c]));
}

// ------------- dense GEMM: H[n][COUT] = X[n][128] @ W[128][COUT], bf16 out -------------

template <int COUT>
__global__ __launch_bounds__(256) void gemm_k(const float* __restrict__ X,
                                              const float* __restrict__ W,
                                              __hip_bfloat16* __restrict__ H, int n) {
    constexpr int KT = 64;             // k-tile
    constexpr int CG = COUT / 4;       // thread groups along channels
    constexpr int MG = 256 / CG;       // thread groups along rows
    constexpr int TILE_M = MG * 4;
    __shared__ float xs[TILE_M][KT];
    __shared__ float ws[KT][COUT];
    const int t = threadIdx.x;
    const int m_base = blockIdx.x * TILE_M;
    const int tx = t % CG, ty = t / CG;
    const int c0 = tx * 4, m0 = ty * 4;
    float acc[4][4] = {};
    for (int kt = 0; kt < 128; kt += KT) {
        {   // stage W tile (KT x COUT), linear copy
            const float4* src = (const float4*)(W + (size_t)kt * COUT);
            float4* dst = (float4*)&ws[0][0];
            constexpr int NW = KT * COUT / 4 / 256;
#pragma unroll
            for (int i = 0; i < NW; i++) dst[t + i * 256] = src[t + i * 256];
        }
        {   // stage X tile (TILE_M x KT)
            float4* dst = (float4*)&xs[0][0];
            constexpr int NX = TILE_M * KT / 4 / 256;
#pragma unroll
            for (int i = 0; i < NX; i++) {
                int idx = t + i * 256;
                int m = idx >> 4, q = idx & 15;  // 16 float4 per row of KT
                int gm = m_base + m;
                float4 v = make_float4(0.f, 0.f, 0.f, 0.f);
                if (gm < n) v = ((const float4*)X)[(size_t)gm * 32 + (kt >> 2) + q];
                dst[idx] = v;
            }
        }
        __syncthreads();
#pragma unroll
        for (int k = 0; k < KT; k += 4) {
            float xr[4][4], wr[4][4];
#pragma unroll
            for (int mm = 0; mm < 4; mm++) {
                float4 v = *(const float4*)&xs[m0 + mm][k];
                xr[mm][0] = v.x; xr[mm][1] = v.y; xr[mm][2] = v.z; xr[mm][3] = v.w;
            }
#pragma unroll
            for (int kk = 0; kk < 4; kk++) {
                float4 v = *(const float4*)&ws[k + kk][c0];
                wr[kk][0] = v.x; wr[kk][1] = v.y; wr[kk][2] = v.z; wr[kk][3] = v.w;
            }
#pragma unroll
            for (int kk = 0; kk < 4; kk++)
#pragma unroll
                for (int mm = 0; mm < 4; mm++)
#pragma unroll
                    for (int cc = 0; cc < 4; cc++)
                        acc[mm][cc] = fmaf(xr[mm][kk], wr[kk][cc], acc[mm][cc]);
        }
        __syncthreads();
    }
#pragma unroll
    for (int mm = 0; mm < 4; mm++) {
        int gm = m_base + m0 + mm;
        if (gm < n) {
            ushort4 o;
            o.x = f2bf(acc[mm][0]); o.y = f2bf(acc[mm][1]);
            o.z = f2bf(acc[mm][2]); o.w = f2bf(acc[mm][3]);
            *(ushort4*)&H[(size_t)gm * COUT + c0] = o;
        }
    }
}

// ---------------- aggregation: one wave per node (bf16 gathers) ----------------

// C=128: lane handles 2 channels (one packed bf16x2 = 4B load). relu(agg + b).
__global__ __launch_bounds__(256) void k_agg128(const __hip_bfloat16* __restrict__ h,
                                                const int* __restrict__ indptr,
                                                const int2* __restrict__ csr,
                                                const float* __restrict__ dinv,
                                                const float* __restrict__ bias,
                                                float* __restrict__ out, int n) {
    int wid = (blockIdx.x * blockDim.x + threadIdx.x) >> 6;
    int lane = threadIdx.x & 63;
    if (wid >= n) return;
    const unsigned int* hp = (const unsigned int*)h;  // 2 bf16 per uint, 64/row
    float di = dinv[wid];
    float wself = di * di;
    float2 hv = bf2_to_f2(hp[(size_t)wid * 64 + lane]);
    float2 a[8];
#pragma unroll
    for (int k = 0; k < 8; k++) a[k] = make_float2(0.f, 0.f);
    a[0].x = wself * hv.x;
    a[0].y = wself * hv.y;
    int e = indptr[wid], e1 = indptr[wid + 1];
    for (; e + 8 <= e1; e += 8) {
        int2 c[8];
#pragma unroll
        for (int k = 0; k < 8; k++) c[k] = csr[e + k];
#pragma unroll
        for (int k = 0; k < 8; k++) {
            float nr = __int_as_float(c[k].y);
            float2 v = bf2_to_f2(hp[(size_t)c[k].x * 64 + lane]);
            a[k].x = fmaf(nr, v.x, a[k].x);
            a[k].y = fmaf(nr, v.y, a[k].y);
        }
    }
    for (; e < e1; e++) {
        int2 ck = csr[e];
        float nr = __int_as_float(ck.y);
        float2 v = bf2_to_f2(hp[(size_t)ck.x * 64 + lane]);
        a[0].x = fmaf(nr, v.x, a[0].x);
        a[0].y = fmaf(nr, v.y, a[0].y);
    }
    float sx = ((a[0].x + a[1].x) + (a[2].x + a[3].x)) +
               ((a[4].x + a[5].x) + (a[6].x + a[7].x));
    float sy = ((a[0].y + a[1].y) + (a[2].y + a[3].y)) +
               ((a[4].y + a[5].y) + (a[6].y + a[7].y));
    float2 b = ((const float2*)bias)[lane];
    ((float2*)(out + (size_t)wid * 128))[lane] =
        make_float2(fmaxf(sx + b.x, 0.f), fmaxf(sy + b.y, 0.f));
}

// C=64: lane handles 1 channel (2B bf16 load; 128B/row = 1 cache line).
__global__ __launch_bounds__(256) void k_agg64(const __hip_bfloat16* __restrict__ h,
                                               const int* __restrict__ indptr,
                                               const int2* __restrict__ csr,
                                               const float* __restrict__ dinv,
                                               const float* __restrict__ bias,
                                               float* __restrict__ out, int n) {
    int wid = (blockIdx.x * blockDim.x + threadIdx.x) >> 6;
    int lane = threadIdx.x & 63;
    if (wid >= n) return;
    const unsigned short* hp = (const unsigned short*)h;
    float di = dinv[wid];
    float a[8];
#pragma unroll
    for (int k = 0; k < 8; k++) a[k] = 0.f;
    a[0] = di * di * bf_to_f(hp[(size_t)wid * 64 + lane]);
    int e = indptr[wid], e1 = indptr[wid + 1];
    for (; e + 8 <= e1; e += 8) {
        int2 c[8];
#pragma unroll
        for (int k = 0; k < 8; k++) c[k] = csr[e + k];
#pragma unroll
        for (int k = 0; k < 8; k++) {
            float nr = __int_as_float(c[k].y);
            a[k] = fmaf(nr, bf_to_f(hp[(size_t)c[k].x * 64 + lane]), a[k]);
        }
    }
    for (; e < e1; e++) {
        int2 ck = csr[e];
        float nr = __int_as_float(ck.y);
        a[0] = fmaf(nr, bf_to_f(hp[(size_t)ck.x * 64 + lane]), a[0]);
    }
    float s = ((a[0] + a[1]) + (a[2] + a[3])) + ((a[4] + a[5]) + (a[6] + a[7]));
    out[(size_t)wid * 64 + lane] = s + bias[lane];
}

// ---------------- launch ----------------

extern "C" void kernel_launch(void* const* d_in, const int* in_sizes, int n_in,
                              void* d_out, int out_size, void* d_ws, size_t ws_size,
                              hipStream_t stream) {
    const float* x  = (const float*)d_in[0];
    const int* ei   = (const int*)d_in[1];
    const float* W1 = (const float*)d_in[2];
    const float* b1 = (const float*)d_in[3];
    const float* W2 = (const float*)d_in[4];
    const float* b2 = (const float*)d_in[5];
    float* out = (float*)d_out;

    const int N = in_sizes[0] / 128;
    const int E = in_sizes[1] / 2;
    const int* row = ei;       // edge_index[0] = source
    const int* col = ei + E;   // edge_index[1] = target

    char* p = (char*)d_ws;
    auto carve = [&](size_t bytes) -> void* {
        void* r = (void*)p;
        p += (bytes + 255) & ~(size_t)255;
        return r;
    };
    int*   cnt      = (int*)carve((size_t)N * 4);
    float* dinv     = (float*)carve((size_t)N * 4);
    int*   indptr   = (int*)carve((size_t)(N + 1) * 4);
    int*   bsum     = (int*)carve(512 * 4);
    int*   boff     = (int*)carve(512 * 4);
    int*   cursor   = (int*)carve((size_t)N * 4);
    int2*  csr      = (int2*)carve((size_t)E * 8);
    __hip_bfloat16* h  = (__hip_bfloat16*)carve((size_t)N * 128 * 2);  // bf16
    float* h1          = (float*)carve((size_t)N * 128 * 4);
    __hip_bfloat16* h2 = (__hip_bfloat16*)carve((size_t)N * 64 * 2);   // bf16

    const int NB = cdiv(N, 256);  // scan blocks (391 <= 512)

    k_init<<<cdiv(N, 256), 256, 0, stream>>>(cnt, cursor, N);
    k_deg<<<cdiv(E, 256), 256, 0, stream>>>(col, cnt, E);
    k_dinv<<<cdiv(N, 256), 256, 0, stream>>>(cnt, dinv, N);
    k_scan1<<<NB, 256, 0, stream>>>(cnt, indptr, bsum, N);
    k_scan2<<<1, 512, 0, stream>>>(bsum, boff, NB);
    k_scan3<<<cdiv(N + 1, 256), 256, 0, stream>>>(indptr, boff, N, E);
    k_fill<<<cdiv(E, 256), 256, 0, stream>>>(row, col, indptr, cursor, dinv,
                                             csr, E);

    // layer 1: h = bf16(x@W1) ; h1 = relu(agg(h) + b1)
    gemm_k<128><<<cdiv(N, 32), 256, 0, stream>>>(x, W1, h, N);
    k_agg128<<<cdiv(N, 4), 256, 0, stream>>>(h, indptr, csr, dinv, b1, h1, N);
    // layer 2: h2 = bf16(h1@W2) ; out = agg(h2) + b2
    gemm_k<64><<<cdiv(N, 64), 256, 0, stream>>>(h1, W2, h2, N);
    k_agg64<<<cdiv(N, 4), 256, 0, stream>>>(h2, indptr, csr, dinv, b2, out, N);
}